// Round 8
// baseline (553.175 us; speedup 1.0000x reference)
//
#include <hip/hip_runtime.h>
#include <hip/hip_bf16.h>

#define NE   64
#define NH   1024
#define NF   2816
#define TPE  64
#define PITCH  72     // k2 LDS pitch (validated at 7.1 TB/s)
#define WPITCH 1032   // k1 LDS row pitch in ushorts (2064B: rows offset 4 banks -> 2-way max)

typedef __attribute__((ext_vector_type(8))) short bf16x8;
typedef __attribute__((ext_vector_type(4))) float f32x4;

__device__ __forceinline__ ushort f2bf(float f) {
    union { float f; unsigned u; } v; v.f = f;
    unsigned r = v.u + 0x7fffu + ((v.u >> 16) & 1u);
    return (ushort)(r >> 16);
}

__device__ __forceinline__ bf16x8 cvt8(f32x4 lo, f32x4 hi) {
    bf16x8 r;
    #pragma unroll
    for (int j = 0; j < 4; ++j) {
        r[j]     = (short)f2bf(lo[j]);
        r[4 + j] = (short)f2bf(hi[j]);
    }
    return r;
}

// ---------------- Kernel 0: x (f32) -> xb (bf16), one pass -----------------
__global__ __launch_bounds__(256)
void xcast(const float* __restrict__ x, ushort* __restrict__ xb) {
    const int i = blockIdx.x * 256 + threadIdx.x;   // 8 elems per thread
    const f32x4 a = *(const f32x4*)(x + (size_t)i * 8);
    const f32x4 b = *(const f32x4*)(x + (size_t)i * 8 + 4);
    *(bf16x8*)(xb + (size_t)i * 8) = cvt8(a, b);
}

// ---------------- Kernel 1: gated = silu(x@w1^T) * (x@w3^T), bf16 out ----------
// DRAM-locality layout: block = 16 f-rows x FULL H. Stage = one shot of
// 16 rows x 4KB x 2 matrices read as contiguous streams (2KB per wave instr,
// rows sequential) -> reg cvt -> bf16 LDS. ONE barrier, then 32 barrier-free
// K-iters (A-frag per-lane from L2-resident bf16 x; 2 LDS b128 + 2 MFMA).
// grid (NF/16, NE) = (176, 64); LDS 64.5 KB -> 2 blocks/CU (stage of one
// overlaps compute of the other).
__global__ __launch_bounds__(256, 2)
void k1_gate(const ushort* __restrict__ xb,
             const float* __restrict__ w1,
             const float* __restrict__ w3,
             ushort* __restrict__ g) {
    __shared__ ushort lW1[16 * WPITCH];   // 32.25 KB
    __shared__ ushort lW3[16 * WPITCH];   // 32.25 KB

    const int jt   = blockIdx.x;               // f 16-row slice (0..175)
    const int e    = blockIdx.y;               // expert
    const int tid  = threadIdx.x;
    const int lane = tid & 63;
    const int wid  = tid >> 6;
    const int m15  = lane & 15;
    const int hi   = lane >> 4;
    const int mrow = wid * 16 + m15;           // token row this lane feeds A

    const float* B1 = w1 + ((size_t)e * NF + (size_t)jt * 16) * NH;
    const float* B3 = w3 + ((size_t)e * NF + (size_t)jt * 16) * NH;

    // ---- stage: 2048 float4-pairs per matrix; 8 rounds x 256 threads.
    // pair p: row = p>>7 (16 rows), colp = p&127 -> 32B contiguous per thread,
    // 2KB contiguous per wave instruction, rows walked in order.
    #pragma unroll
    for (int r = 0; r < 8; ++r) {
        const int p    = r * 256 + tid;
        const int row  = p >> 7;
        const int colp = p & 127;
        const size_t goff = (size_t)row * NH + (size_t)colp * 8;
        const f32x4 a1 = *(const f32x4*)(B1 + goff);
        const f32x4 b1 = *(const f32x4*)(B1 + goff + 4);
        const f32x4 a3 = *(const f32x4*)(B3 + goff);
        const f32x4 b3 = *(const f32x4*)(B3 + goff + 4);
        *(bf16x8*)(&lW1[row * WPITCH + colp * 8]) = cvt8(a1, b1);
        *(bf16x8*)(&lW3[row * WPITCH + colp * 8]) = cvt8(a3, b3);
    }
    __syncthreads();

    // ---- compute: 32 K-iters, no barriers. A from global bf16 x (L2-hot).
    f32x4 acc1 = f32x4{0.f, 0.f, 0.f, 0.f};
    f32x4 acc3 = f32x4{0.f, 0.f, 0.f, 0.f};
    const ushort* xrow = xb + ((size_t)e * TPE + mrow) * NH;

    #pragma unroll 8
    for (int kk = 0; kk < 32; ++kk) {
        const int ko = kk * 32 + hi * 8;
        const bf16x8 af = *(const bf16x8*)(xrow + ko);
        const bf16x8 b1 = *(const bf16x8*)(&lW1[m15 * WPITCH + ko]);
        acc1 = __builtin_amdgcn_mfma_f32_16x16x32_bf16(af, b1, acc1, 0, 0, 0);
        const bf16x8 b3 = *(const bf16x8*)(&lW3[m15 * WPITCH + ko]);
        acc3 = __builtin_amdgcn_mfma_f32_16x16x32_bf16(af, b3, acc3, 0, 0, 0);
    }

    // ---- epilogue: SwiGLU. C/D: col(m15)=f within 16, row(hi*4+i)=token in wave tile
    #pragma unroll
    for (int i = 0; i < 4; ++i) {
        const float h1v = acc1[i];
        const float h3v = acc3[i];
        const float s   = (h1v / (1.f + __expf(-h1v))) * h3v;
        const int row = wid * 16 + hi * 4 + i;
        const int col = jt * 16 + m15;
        g[((size_t)e * TPE + row) * NF + col] = f2bf(s);
    }
}

// ---------------- Kernel 2: out = gated @ w2 (per expert), fp32 out ------------
// (unchanged — ~104 us at ~7.1 TB/s on w2; at roofline)
__global__ __launch_bounds__(256, 2)
void k2_down(const ushort* __restrict__ g,
             const float* __restrict__ w2,
             float* __restrict__ out) {
    __shared__ ushort lA[64 * PITCH];
    __shared__ ushort lB[64 * PITCH];

    const int jt   = blockIdx.x;
    const int e    = blockIdx.y;
    const int tid  = threadIdx.x;
    const int lane = tid & 63;
    const int wid  = tid >> 6;

    const ushort* A = g  + (size_t)e * TPE * NF;
    const float*  B = w2 + (size_t)e * NF * NH + (size_t)jt * 64;
    float* O = out + (size_t)e * TPE * NH + (size_t)jt * 64;

    f32x4 acc[4];
    for (int nf = 0; nf < 4; ++nf) acc[nf] = f32x4{0.f, 0.f, 0.f, 0.f};

    for (int kt = 0; kt < NF / 64; ++kt) {   // 44 iters
        __syncthreads();
        #pragma unroll
        for (int r = 0; r < 2; ++r) {
            const int q   = tid + r * 256;
            const int row = q >> 3;
            const int k8  = (q & 7) * 8;
            *(bf16x8*)(&lA[row * PITCH + k8]) =
                *(const bf16x8*)(A + (size_t)row * NF + kt * 64 + k8);
        }
        {
            const int n  = tid & 63;
            const int kq = (tid >> 6) * 4;
            #pragma unroll
            for (int r = 0; r < 4; ++r) {
                const int ks = kq + r * 16;
                const size_t base = (size_t)(kt * 64 + ks) * NH + n;
                const float f0 = B[base];
                const float f1 = B[base + NH];
                const float f2 = B[base + 2 * (size_t)NH];
                const float f3 = B[base + 3 * (size_t)NH];
                ushort4 b;
                b.x = f2bf(f0); b.y = f2bf(f1); b.z = f2bf(f2); b.w = f2bf(f3);
                *(ushort4*)(&lB[n * PITCH + ks]) = b;
            }
        }
        __syncthreads();

        const int mrow = wid * 16 + (lane & 15);
        #pragma unroll
        for (int ks = 0; ks < 2; ++ks) {
            const int koff = ks * 32 + ((lane >> 4) * 8);
            const bf16x8 af = *(const bf16x8*)(&lA[mrow * PITCH + koff]);
            #pragma unroll
            for (int nf = 0; nf < 4; ++nf) {
                const bf16x8 bfr = *(const bf16x8*)(&lB[(nf * 16 + (lane & 15)) * PITCH + koff]);
                acc[nf] = __builtin_amdgcn_mfma_f32_16x16x32_bf16(af, bfr, acc[nf], 0, 0, 0);
            }
        }
    }

    #pragma unroll
    for (int nf = 0; nf < 4; ++nf) {
        #pragma unroll
        for (int i = 0; i < 4; ++i) {
            const int row = wid * 16 + ((lane >> 4) * 4) + i;
            const int col = nf * 16 + (lane & 15);
            O[(size_t)row * NH + col] = acc[nf][i];
        }
    }
}

extern "C" void kernel_launch(void* const* d_in, const int* in_sizes, int n_in,
                              void* d_out, int out_size, void* d_ws, size_t ws_size,
                              hipStream_t stream) {
    const float* x  = (const float*)d_in[0];
    const float* w1 = (const float*)d_in[2];
    const float* w3 = (const float*)d_in[3];
    const float* w2 = (const float*)d_in[4];
    float* out = (float*)d_out;
    ushort* gated = (ushort*)d_ws;                         // 23.1 MB
    ushort* xbf   = (ushort*)((char*)d_ws + (32u << 20));  // 8.4 MB @ +32MB

    xcast<<<dim3((TPE * NE * NH) / (256 * 8)), dim3(256), 0, stream>>>(x, xbf);

    dim3 g1(NF / 16, NE);    // (176, 64)
    k1_gate<<<g1, dim3(256), 0, stream>>>(xbf, w1, w3, gated);

    dim3 g2(NH / 64, NE);    // (16, 64)
    k2_down<<<g2, dim3(256), 0, stream>>>(gated, w2, out);
}

// Round 9
// 504.628 us; speedup vs baseline: 1.0962x; 1.0962x over previous
//
#include <hip/hip_runtime.h>
#include <hip/hip_bf16.h>

#define NE   64
#define NH   1024
#define NF   2816
#define TPE  64
#define PITCH 72      // LDS pitch (validated in k2 at ~7 TB/s)

typedef __attribute__((ext_vector_type(8))) short bf16x8;
typedef __attribute__((ext_vector_type(4))) float f32x4;

__device__ __forceinline__ ushort f2bf(float f) {
    union { float f; unsigned u; } v; v.f = f;
    unsigned r = v.u + 0x7fffu + ((v.u >> 16) & 1u);
    return (ushort)(r >> 16);
}

__device__ __forceinline__ float bf2f(ushort u) {
    union { unsigned u; float f; } v; v.u = ((unsigned)u) << 16;
    return v.f;
}

__device__ __forceinline__ bf16x8 cvt8(f32x4 lo, f32x4 hi) {
    bf16x8 r;
    #pragma unroll
    for (int j = 0; j < 4; ++j) {
        r[j]     = (short)f2bf(lo[j]);
        r[4 + j] = (short)f2bf(hi[j]);
    }
    return r;
}

// ---------------- Kernel 0: x (f32) -> xb (bf16), one pass -----------------
__global__ __launch_bounds__(256)
void xcast(const float* __restrict__ x, ushort* __restrict__ xb) {
    const int i = blockIdx.x * 256 + threadIdx.x;   // 8 elems per thread
    const f32x4 a = *(const f32x4*)(x + (size_t)i * 8);
    const f32x4 b = *(const f32x4*)(x + (size_t)i * 8 + 4);
    *(bf16x8*)(xb + (size_t)i * 8) = cvt8(a, b);
}

// ---- Kernel 1a/1b: single-weight-stream GEMM, x @ w^T (per expert) ----------
// GATE=0: out_h = x@w1^T (bf16).   GATE=1: gated = silu(h1) * (x@w3^T) (bf16).
// ONE 738MB weight stream per kernel (test of the DRAM bank-thrash theory —
// every fused-k1 variant with two interleaved weight streams pinned at
// ~4.4 TB/s; single-stream k2 does ~7). Structure = k2's: serial 2-barrier,
// reg-staged float4->cvt->ushort4, 9.2 KB LDS, A per-lane from L2-resident xb.
template <int GATE>
__global__ __launch_bounds__(256, 2)
void k1_mm(const ushort* __restrict__ xb,
           const float* __restrict__ w,
           const ushort* __restrict__ h1in,
           ushort* __restrict__ outp) {
    __shared__ ushort lW[64 * PITCH];   // 9.2 KB

    const int jt   = blockIdx.x;               // ff 64-tile (0..43)
    const int e    = blockIdx.y;               // expert
    const int tid  = threadIdx.x;
    const int lane = tid & 63;
    const int wid  = tid >> 6;
    const int m15  = lane & 15;
    const int hi   = lane >> 4;
    const int mrow = wid * 16 + m15;

    const ushort* xA = xb + ((size_t)e * TPE + mrow) * NH;
    const float*  B  = w  + ((size_t)e * NF + (size_t)jt * 64) * NH;

    f32x4 acc[4];
    #pragma unroll
    for (int nf = 0; nf < 4; ++nf) acc[nf] = f32x4{0.f, 0.f, 0.f, 0.f};

    const int srow = tid >> 4;         // staging row base (0..15)
    const int sc4  = (tid & 15) * 4;   // staging dword col

    for (int kt = 0; kt < NH / 64; ++kt) {     // 16 iters
        const size_t kb = (size_t)kt * 64;
        __syncthreads();                        // readers done with LDS
        // stage w (64 rows x 64 k f32): 4 rounds of float4 -> cvt -> ushort4
        #pragma unroll
        for (int r = 0; r < 4; ++r) {
            const int row = srow + r * 16;
            const float4 v = *(const float4*)(B + (size_t)row * NH + kb + sc4);
            ushort4 u;
            u.x = f2bf(v.x); u.y = f2bf(v.y); u.z = f2bf(v.z); u.w = f2bf(v.w);
            *(ushort4*)(&lW[row * PITCH + sc4]) = u;
        }
        __syncthreads();                        // tile staged

        #pragma unroll
        for (int ks = 0; ks < 2; ++ks) {
            const int koff = ks * 32 + hi * 8;
            const bf16x8 af = *(const bf16x8*)(xA + kb + koff);  // L2-hot x
            #pragma unroll
            for (int nf = 0; nf < 4; ++nf) {
                const bf16x8 bw = *(const bf16x8*)(&lW[(nf * 16 + m15) * PITCH + koff]);
                acc[nf] = __builtin_amdgcn_mfma_f32_16x16x32_bf16(af, bw, acc[nf], 0, 0, 0);
            }
        }
    }

    // epilogue. C/D layout: col=lane&15, row=(lane>>4)*4+i
    #pragma unroll
    for (int nf = 0; nf < 4; ++nf) {
        #pragma unroll
        for (int i = 0; i < 4; ++i) {
            const int row = wid * 16 + hi * 4 + i;
            const int col = jt * 64 + nf * 16 + m15;
            const size_t idx = ((size_t)e * TPE + row) * NF + col;
            if (GATE) {
                const float h1v = bf2f(h1in[idx]);          // L2/L3-resident
                const float h3v = acc[nf][i];
                const float s   = (h1v / (1.f + __expf(-h1v))) * h3v;
                outp[idx] = f2bf(s);
            } else {
                outp[idx] = f2bf(acc[nf][i]);
            }
        }
    }
}

// ---------------- Kernel 2: out = gated @ w2 (per expert), fp32 out ------------
// (unchanged — single weight stream at ~7 TB/s; at roofline)
__global__ __launch_bounds__(256, 2)
void k2_down(const ushort* __restrict__ g,
             const float* __restrict__ w2,
             float* __restrict__ out) {
    __shared__ ushort lA[64 * PITCH];
    __shared__ ushort lB[64 * PITCH];

    const int jt   = blockIdx.x;
    const int e    = blockIdx.y;
    const int tid  = threadIdx.x;
    const int lane = tid & 63;
    const int wid  = tid >> 6;

    const ushort* A = g  + (size_t)e * TPE * NF;
    const float*  B = w2 + (size_t)e * NF * NH + (size_t)jt * 64;
    float* O = out + (size_t)e * TPE * NH + (size_t)jt * 64;

    f32x4 acc[4];
    for (int nf = 0; nf < 4; ++nf) acc[nf] = f32x4{0.f, 0.f, 0.f, 0.f};

    for (int kt = 0; kt < NF / 64; ++kt) {   // 44 iters
        __syncthreads();
        #pragma unroll
        for (int r = 0; r < 2; ++r) {
            const int q   = tid + r * 256;
            const int row = q >> 3;
            const int k8  = (q & 7) * 8;
            *(bf16x8*)(&lA[row * PITCH + k8]) =
                *(const bf16x8*)(A + (size_t)row * NF + kt * 64 + k8);
        }
        {
            const int n  = tid & 63;
            const int kq = (tid >> 6) * 4;
            #pragma unroll
            for (int r = 0; r < 4; ++r) {
                const int ks = kq + r * 16;
                const size_t base = (size_t)(kt * 64 + ks) * NH + n;
                const float f0 = B[base];
                const float f1 = B[base + NH];
                const float f2 = B[base + 2 * (size_t)NH];
                const float f3 = B[base + 3 * (size_t)NH];
                ushort4 b;
                b.x = f2bf(f0); b.y = f2bf(f1); b.z = f2bf(f2); b.w = f2bf(f3);
                *(ushort4*)(&lB[n * PITCH + ks]) = b;
            }
        }
        __syncthreads();

        const int mrow = wid * 16 + (lane & 15);
        #pragma unroll
        for (int ks = 0; ks < 2; ++ks) {
            const int koff = ks * 32 + ((lane >> 4) * 8);
            const bf16x8 af = *(const bf16x8*)(&lA[mrow * PITCH + koff]);
            #pragma unroll
            for (int nf = 0; nf < 4; ++nf) {
                const bf16x8 bfr = *(const bf16x8*)(&lB[(nf * 16 + (lane & 15)) * PITCH + koff]);
                acc[nf] = __builtin_amdgcn_mfma_f32_16x16x32_bf16(af, bfr, acc[nf], 0, 0, 0);
            }
        }
    }

    #pragma unroll
    for (int nf = 0; nf < 4; ++nf) {
        #pragma unroll
        for (int i = 0; i < 4; ++i) {
            const int row = wid * 16 + ((lane >> 4) * 4) + i;
            const int col = nf * 16 + (lane & 15);
            O[(size_t)row * NH + col] = acc[nf][i];
        }
    }
}

extern "C" void kernel_launch(void* const* d_in, const int* in_sizes, int n_in,
                              void* d_out, int out_size, void* d_ws, size_t ws_size,
                              hipStream_t stream) {
    const float* x  = (const float*)d_in[0];
    const float* w1 = (const float*)d_in[2];
    const float* w3 = (const float*)d_in[3];
    const float* w2 = (const float*)d_in[4];
    float* out = (float*)d_out;
    ushort* gated = (ushort*)d_ws;                         // 23.1 MB
    ushort* xbf   = (ushort*)((char*)d_ws + (32u << 20));  // 8.4 MB @ +32MB
    ushort* h1    = (ushort*)((char*)d_ws + (48u << 20));  // 23.1 MB @ +48MB

    xcast<<<dim3((TPE * NE * NH) / (256 * 8)), dim3(256), 0, stream>>>(x, xbf);

    dim3 g1(NF / 64, NE);    // (44, 64) jt-major
    k1_mm<0><<<g1, dim3(256), 0, stream>>>(xbf, w1, nullptr, h1);   // h1 = x@w1^T
    k1_mm<1><<<g1, dim3(256), 0, stream>>>(xbf, w3, h1, gated);     // gated = silu(h1)*x@w3^T

    dim3 g2(NH / 64, NE);    // (16, 64)
    k2_down<<<g2, dim3(256), 0, stream>>>(gated, w2, out);
}